// Round 2
// baseline (331.501 us; speedup 1.0000x reference)
//
#include <hip/hip_runtime.h>
#include <stdint.h>

// Problem constants (fixed by reference setup_inputs): x (32,384,56,56) fp32,
// weight (384,384) fp32, bias (384,) fp32. K=7 horizontal cyclic shifts.
#define B_   32
#define C_   384
#define H_   56
#define W_   56
#define HW_  (H_*W_)        // 3136
#define NWORD 6             // 384 / 64 bits

// dx(c) = (c + 3) % 7 - 3  ->  c%7 = 0..6 : {0,1,2,3,-3,-2,-1}

// ---------------------------------------------------------------------------
// Compile-time tables.
// inv[pat][k]: bit c of word k set <=> channel c is out-of-bounds for edge
// pattern pat (pat = w for w<3, 3 for interior, w-49 for w>=53).
// invw[w][k]: same, indexed directly by w (for the pack phase).
// ---------------------------------------------------------------------------
struct Masks {
    unsigned long long inv[7][NWORD];
    int nvalid[7];
};
constexpr Masks make_masks() {
    Masks m{};
    int wv[7] = {0, 1, 2, 3, 53, 54, 55};
    for (int p = 0; p < 7; ++p) {
        int nv = 0;
        for (int c = 0; c < C_; ++c) {
            int dx = (c + 3) % 7 - 3;
            int wp = wv[p] + dx;
            if (wp >= 0 && wp < W_) nv++;
            else m.inv[p][c >> 6] |= 1ull << (c & 63);
        }
        m.nvalid[p] = nv;
    }
    return m;
}
__device__ constexpr Masks MK = make_masks();

struct InvW { unsigned long long m[W_][NWORD]; };
constexpr InvW make_invw() {
    InvW t{};
    for (int w = 0; w < W_; ++w)
        for (int c = 0; c < C_; ++c) {
            int dx = (c + 3) % 7 - 3;
            int wp = w + dx;
            if (!(wp >= 0 && wp < W_)) t.m[w][c >> 6] |= 1ull << (c & 63);
        }
    return t;
}
__device__ constexpr InvW IVW = make_invw();

// ---------------------------------------------------------------------------
// Prep: pack sign(weight) into 6 uint64 per output channel via __ballot, and
// build C2[o][pat] = Nvalid(pat) + 2*popcount(wbits & inv(pat)) + bias[o].
// out = C2[o][pat] - 2*popcount(xm ^ wbits)  with invalid x-bits forced to 0.
// ---------------------------------------------------------------------------
__global__ __launch_bounds__(64) void prep_kernel(
        const float* __restrict__ weight, const float* __restrict__ bias,
        unsigned long long* __restrict__ pw, float* __restrict__ C2) {
    int o = blockIdx.x;
    int lane = threadIdx.x;
    unsigned long long words[NWORD];
#pragma unroll
    for (int k = 0; k < NWORD; ++k) {
        float v = weight[o * C_ + k * 64 + lane];
        words[k] = __ballot(v < 0.0f);   // bit c set <=> sign(weight)==-1
    }
    if (lane < NWORD) pw[o * NWORD + lane] = words[lane];
    if (lane < 7) {
        int wb = 0;
#pragma unroll
        for (int k = 0; k < NWORD; ++k)
            wb += __popcll(words[k] & MK.inv[lane][k]);
        C2[o * 7 + lane] = (float)(MK.nvalid[lane] + 2 * wb) + bias[o];
    }
}

// ---------------------------------------------------------------------------
// pack_word<K>: build the 64-channel sign word for channel-word K at pixel
// column w. K is a template parameter so dx and the bit position fold at
// compile time. Loads are coalesced across lanes (lane = w).
// ---------------------------------------------------------------------------
template <int K>
__device__ __forceinline__ unsigned long long pack_word(
        const float* __restrict__ xb, int w) {
    constexpr int dxt[7] = {0, 1, 2, 3, -3, -2, -1};
    unsigned long long bits = 0;
#pragma unroll
    for (int j = 0; j < 64; ++j) {
        int dx = dxt[(K * 64 + j) % 7];          // folds after unroll
        int wp = w + dx;
        int wpc = wp < 0 ? 0 : (wp > W_ - 1 ? W_ - 1 : wp);  // clamp (masked later)
        unsigned u = __float_as_uint(
            __builtin_nontemporal_load(&xb[(size_t)j * HW_ + wpc]));
        bits |= (unsigned long long)(u >> 31) << j;
    }
    return bits & ~IVW.m[w][K];                  // zero out-of-bounds channels
}

// ---------------------------------------------------------------------------
// Fused kernel: one block per (b, h) row. 384 threads = 6 waves.
//   Phase 1 (pack): wave wid packs channel-word k = wid for all 56 pixels of
//     the row (lane = pixel column; 56/64 lanes active) into LDS xs[6][56].
//     Loads are coalesced (224 B contiguous per instruction), x is read
//     exactly once grid-wide; no packed intermediate ever touches HBM.
//   Phase 2 (gemm): after one barrier, wave wid computes output channels
//     o = wid*64 .. wid*64+63 for its pixel: 6x (xor + popcll) against
//     wave-uniform weights (s_load from K$), nontemporal stores coalesced
//     on the pixel axis (224 B per instruction).
// Grid = 32*56 = 1792 blocks x 6 waves = 42 waves/CU of schedulable work
// (vs the old fallback's 1.5 waves/SIMD, which was latency-bound).
// ---------------------------------------------------------------------------
__global__ __launch_bounds__(384) void fused_kernel(
        const float* __restrict__ x,
        const unsigned long long* __restrict__ pw,
        const float* __restrict__ C2,
        float* __restrict__ out) {
    __shared__ unsigned long long xs[NWORD][W_];   // 2688 B

    int b = blockIdx.x / H_;
    int h = blockIdx.x % H_;
    int wid  = threadIdx.x >> 6;    // wave id 0..5 == channel-word k
    int lane = threadIdx.x & 63;    // pixel column (56 active)

    if (lane < W_) {
        const float* xb = x + ((size_t)b * C_ + wid * 64) * HW_ + h * W_;
        unsigned long long bits;
        switch (wid) {
            case 0: bits = pack_word<0>(xb, lane); break;
            case 1: bits = pack_word<1>(xb, lane); break;
            case 2: bits = pack_word<2>(xb, lane); break;
            case 3: bits = pack_word<3>(xb, lane); break;
            case 4: bits = pack_word<4>(xb, lane); break;
            default: bits = pack_word<5>(xb, lane); break;
        }
        xs[wid][lane] = bits;       // consecutive 8B writes, conflict-free
    }
    __syncthreads();
    if (lane >= W_) return;

    int w = lane;
    unsigned long long xw[NWORD];
#pragma unroll
    for (int k = 0; k < NWORD; ++k)
        xw[k] = xs[k][w];           // consecutive 8B reads, <=2-way (free)

    int pat = (w < 3) ? w : ((w >= 53) ? w - 49 : 3);
    const int obase = wid * 64;     // this wave's 64 output channels
    float* op = out + ((size_t)b * C_ + obase) * HW_ + (size_t)h * W_ + w;

#pragma unroll 4
    for (int oi = 0; oi < 64; ++oi) {
        int o = obase + oi;
        const unsigned long long* wr = pw + o * NWORD;  // uniform -> s_load
        int U = 0;
#pragma unroll
        for (int k = 0; k < NWORD; ++k)
            U += __popcll(xw[k] ^ wr[k]);
        float v = C2[o * 7 + pat] - 2.0f * (float)U;
        __builtin_nontemporal_store(v, &op[(size_t)oi * HW_]);
    }
}

extern "C" void kernel_launch(void* const* d_in, const int* in_sizes, int n_in,
                              void* d_out, int out_size, void* d_ws, size_t ws_size,
                              hipStream_t stream) {
    const float* x      = (const float*)d_in[0];
    const float* weight = (const float*)d_in[1];
    const float* bias   = (const float*)d_in[2];
    float* out = (float*)d_out;

    // ws layout: pw (18432 B) | C2 (10752 B)  -- only ~29 KB needed now.
    unsigned long long* pw = (unsigned long long*)d_ws;
    float* C2 = (float*)((char*)d_ws + C_ * NWORD * sizeof(unsigned long long));

    prep_kernel<<<dim3(C_), dim3(64), 0, stream>>>(weight, bias, pw, C2);
    fused_kernel<<<dim3(B_ * H_), dim3(384), 0, stream>>>(x, pw, C2, out);
}